// Round 7
// baseline (593.773 us; speedup 1.0000x reference)
//
#include <hip/hip_runtime.h>
#include <hip/hip_bf16.h>

typedef __attribute__((ext_vector_type(8))) short bf16x8;
typedef __attribute__((ext_vector_type(4))) float f32x4;

#define D_MODEL 512
#define NHEAD 8
#define HDIM 64
#define SEQ 4096
#define BATCH 2
#define MTOT (BATCH*SEQ)   // 8192

__device__ __forceinline__ unsigned short f2bf(float f) {
  unsigned int u = __builtin_bit_cast(unsigned int, f);
  u += 0x7FFFu + ((u >> 16) & 1u);   // RNE
  return (unsigned short)(u >> 16);
}

// ---------------------------------------------------------------------------
// fp32 -> bf16 bulk convert (vectorized float4 -> ushort4)
// ---------------------------------------------------------------------------
__global__ __launch_bounds__(256)
void cvt_k(const float* __restrict__ src, unsigned short* __restrict__ dst, int n4) {
  int i = blockIdx.x * blockDim.x + threadIdx.x;
  int stride = gridDim.x * blockDim.x;
  for (; i < n4; i += stride) {
    float4 v = ((const float4*)src)[i];
    ushort4 u = { f2bf(v.x), f2bf(v.y), f2bf(v.z), f2bf(v.w) };
    ((ushort4*)dst)[i] = u;
  }
}

// 4 weight matrices in one launch: blockIdx.y picks the tensor.
__global__ __launch_bounds__(256)
void cvt_w4(const float* __restrict__ w0, const float* __restrict__ w1,
            const float* __restrict__ w2, const float* __restrict__ w3,
            unsigned short* __restrict__ dst, int n4each) {
  const float* srcs[4] = { w0, w1, w2, w3 };
  const float* src = srcs[blockIdx.y];
  unsigned short* d = dst + (size_t)blockIdx.y * n4each * 4;
  int i = blockIdx.x * blockDim.x + threadIdx.x;
  int stride = gridDim.x * blockDim.x;
  for (; i < n4each; i += stride) {
    float4 v = ((const float4*)src)[i];
    ushort4 u = { f2bf(v.x), f2bf(v.y), f2bf(v.z), f2bf(v.w) };
    ((ushort4*)(d))[i] = u;
  }
}

// ---------------------------------------------------------------------------
// Fused Q/K/V projection GEMM. Grid (MTOT/128, 12): blockIdx.y>>2 selects
// {Q,K,V}; (blockIdx.y&3)*128 is the 128-wide N-tile within that projection.
// W4 = [Wq;Wk;Wv] contiguous bf16 [3*512,512]. m97 staging structure.
// Q scaled by 1/8 (folds 1/sqrt(Dh)); Q,K written [B,H,S,Dh]; V written
// [B,H,Dh,S] (transposed for PV fragment loads).
// ---------------------------------------------------------------------------
__global__ __launch_bounds__(256)
void gemm_qkv(const unsigned short* __restrict__ A,
              const unsigned short* __restrict__ W4,
              const float* __restrict__ bq, const float* __restrict__ bk,
              const float* __restrict__ bv,
              unsigned short* __restrict__ qw, unsigned short* __restrict__ kw,
              unsigned short* __restrict__ vtw) {
  __shared__ unsigned short Als[128*64];
  __shared__ unsigned short Bls[128*64];
  const int tid = threadIdx.x;
  const int lane = tid & 63, wid = tid >> 6;
  const int wr = wid >> 1, wc = wid & 1;
  const int l15 = lane & 15, l4 = lane >> 4;
  const int m0 = blockIdx.x * 128;
  const int which = blockIdx.y >> 2;            // 0=Q 1=K 2=V
  const int n0 = (blockIdx.y & 3) * 128;
  const unsigned short* Bw = W4 + (size_t)which * D_MODEL * D_MODEL;
  const float* bias = which == 0 ? bq : (which == 1 ? bk : bv);
  unsigned short* outp = which == 0 ? qw : (which == 1 ? kw : vtw);
  const float scale = which == 0 ? 0.125f : 1.0f;
  const int srow = lane >> 3;
  const int scol = (lane & 7) * 8;
  f32x4 acc[4][4] = {};

  for (int kt = 0; kt < D_MODEL; kt += 64) {
    #pragma unroll
    for (int j = 0; j < 4; ++j) {
      int r = wid*32 + j*8 + srow;
      __builtin_amdgcn_global_load_lds(
        (const __attribute__((address_space(1))) unsigned int*)(A + (size_t)(m0 + r)*D_MODEL + kt + scol),
        (__attribute__((address_space(3))) unsigned int*)(&Als[r*64 + scol]), 16, 0, 0);
      __builtin_amdgcn_global_load_lds(
        (const __attribute__((address_space(1))) unsigned int*)(Bw + (size_t)(n0 + r)*D_MODEL + kt + scol),
        (__attribute__((address_space(3))) unsigned int*)(&Bls[r*64 + scol]), 16, 0, 0);
    }
    __syncthreads();
    #pragma unroll
    for (int ks = 0; ks < 2; ++ks) {
      bf16x8 a[4], b[4];
      #pragma unroll
      for (int m = 0; m < 4; ++m)
        a[m] = *(const bf16x8*)&Als[(wr*64 + m*16 + l15)*64 + ks*32 + l4*8];
      #pragma unroll
      for (int n = 0; n < 4; ++n)
        b[n] = *(const bf16x8*)&Bls[(wc*64 + n*16 + l15)*64 + ks*32 + l4*8];
      #pragma unroll
      for (int m = 0; m < 4; ++m)
        #pragma unroll
        for (int n = 0; n < 4; ++n)
          acc[m][n] = __builtin_amdgcn_mfma_f32_16x16x32_bf16(a[m], b[n], acc[m][n], 0, 0, 0);
    }
    __syncthreads();
  }

  #pragma unroll
  for (int n = 0; n < 4; ++n) {
    int gn = n0 + wc*64 + n*16 + l15;
    float bvv = bias[gn];
    int h = gn >> 6, d = gn & 63;
    #pragma unroll
    for (int m = 0; m < 4; ++m) {
      int gmb = m0 + wr*64 + m*16 + l4*4;
      #pragma unroll
      for (int r = 0; r < 4; ++r) {
        int gm = gmb + r;
        int b = gm >> 12, s = gm & 4095;
        float val = (acc[m][n][r] + bvv) * scale;
        if (which != 2)
          outp[((size_t)((b*NHEAD + h)*SEQ + s))*HDIM + d] = f2bf(val);
        else
          outp[((size_t)((b*NHEAD + h)*HDIM + d))*SEQ + s] = f2bf(val);
      }
    }
  }
}

// ---------------------------------------------------------------------------
// Output-projection GEMM (A bf16 ctx, W bf16, fp32 out [M,N]). m97 structure.
// ---------------------------------------------------------------------------
__global__ __launch_bounds__(256)
void gemm_out(const unsigned short* __restrict__ A,
              const unsigned short* __restrict__ Bw,
              const float* __restrict__ bias, float* __restrict__ out) {
  __shared__ unsigned short Als[128*64];
  __shared__ unsigned short Bls[128*64];
  const int tid = threadIdx.x;
  const int lane = tid & 63, wid = tid >> 6;
  const int wr = wid >> 1, wc = wid & 1;
  const int l15 = lane & 15, l4 = lane >> 4;
  const int m0 = blockIdx.x * 128;
  const int n0 = blockIdx.y * 128;
  const int srow = lane >> 3;
  const int scol = (lane & 7) * 8;
  f32x4 acc[4][4] = {};

  for (int kt = 0; kt < D_MODEL; kt += 64) {
    #pragma unroll
    for (int j = 0; j < 4; ++j) {
      int r = wid*32 + j*8 + srow;
      __builtin_amdgcn_global_load_lds(
        (const __attribute__((address_space(1))) unsigned int*)(A + (size_t)(m0 + r)*D_MODEL + kt + scol),
        (__attribute__((address_space(3))) unsigned int*)(&Als[r*64 + scol]), 16, 0, 0);
      __builtin_amdgcn_global_load_lds(
        (const __attribute__((address_space(1))) unsigned int*)(Bw + (size_t)(n0 + r)*D_MODEL + kt + scol),
        (__attribute__((address_space(3))) unsigned int*)(&Bls[r*64 + scol]), 16, 0, 0);
    }
    __syncthreads();
    #pragma unroll
    for (int ks = 0; ks < 2; ++ks) {
      bf16x8 a[4], b[4];
      #pragma unroll
      for (int m = 0; m < 4; ++m)
        a[m] = *(const bf16x8*)&Als[(wr*64 + m*16 + l15)*64 + ks*32 + l4*8];
      #pragma unroll
      for (int n = 0; n < 4; ++n)
        b[n] = *(const bf16x8*)&Bls[(wc*64 + n*16 + l15)*64 + ks*32 + l4*8];
      #pragma unroll
      for (int m = 0; m < 4; ++m)
        #pragma unroll
        for (int n = 0; n < 4; ++n)
          acc[m][n] = __builtin_amdgcn_mfma_f32_16x16x32_bf16(a[m], b[n], acc[m][n], 0, 0, 0);
    }
    __syncthreads();
  }

  #pragma unroll
  for (int n = 0; n < 4; ++n) {
    int gn = n0 + wc*64 + n*16 + l15;
    float bv = bias[gn];
    #pragma unroll
    for (int m = 0; m < 4; ++m) {
      int gmb = m0 + wr*64 + m*16 + l4*4;
      #pragma unroll
      for (int r = 0; r < 4; ++r)
        out[(size_t)(gmb + r)*D_MODEL + gn] = acc[m][n][r] + bv;
    }
  }
}

// ---------------------------------------------------------------------------
// Flash attention, SWAPPED-operand form (ds-op diet: 50 -> 10 per tile).
// Grid: 1024 blocks (1-D), XCD-swizzled: swz=(bid&7)*128+(bid>>3) so each XCD
// serves only 2 heads -> K/V working set 2 MB, fits the 4 MB per-XCD L2 (T1).
// Block: 256 threads = 4 independent waves, 16 q each.
// QK^T computed as mfma(K, Q) -> s[n][r] = S[key=kt+n*16+l4*4+r][q=l15]:
//   each lane owns one q (l15) and 16 keys -> max/sum are in-register trees
//   + 2 shfl_xor (16, 32) instead of 4x4 shfl.
// P[q][key]: lane's 4 consecutive keys pack to one ds_write_b64 (4 writes).
// PV computed as mfma(V^T, P) -> o[n][r] = O[d=n*16+l4*4+r][q=l15].
// T5 setprio around MFMA clusters; T13 defer-max (THR=8); K ping-pong
// prefetch + V loads issued right after QK^T (latency hides under softmax).
// ---------------------------------------------------------------------------
__global__ __launch_bounds__(256)
void attn_k(const unsigned short* __restrict__ qw,
            const unsigned short* __restrict__ kw,
            const unsigned short* __restrict__ vtw,
            unsigned short* __restrict__ ctx) {
  __shared__ unsigned short Pls[4][16*72];
  const int tid = threadIdx.x;
  const int lane = tid & 63, wid = tid >> 6;
  const int l15 = lane & 15, l4 = lane >> 4;
  const int bid = blockIdx.x;
  const int swz = (bid & 7) * 128 + (bid >> 3);   // bijective: 1024 = 8*128
  const int bh = swz >> 6;                        // b*8 + h, 0..15
  const int q0 = (swz & 63) * 64 + wid * 16;      // this wave's first q row
  const unsigned short* qb = qw + (size_t)bh * SEQ * HDIM;
  const unsigned short* kb = kw + (size_t)bh * SEQ * HDIM;
  const unsigned short* vb = vtw + (size_t)bh * HDIM * SEQ;
  unsigned short* Pw = &Pls[wid][0];

  // Q fragments (B-operand): col=l15 <-> q, k=l4*8+j <-> d.
  bf16x8 qf[2];
  qf[0] = *(const bf16x8*)&qb[(size_t)(q0 + l15)*HDIM + l4*8];
  qf[1] = *(const bf16x8*)&qb[(size_t)(q0 + l15)*HDIM + 32 + l4*8];

  f32x4 o[4] = {};                 // o[n][r] = O[d=n*16+l4*4+r][q=l15]
  float mrow = -1e30f, lrow = 0.f; // scalar per lane (one q per lane)

  // K ping-pong buffers (A-operand: row=l15 <-> key, k=d); preload tile 0.
  bf16x8 kfA[4][2], kfB[4][2];
  #pragma unroll
  for (int n = 0; n < 4; ++n) {
    kfA[n][0] = *(const bf16x8*)&kb[(size_t)(n*16 + l15)*HDIM + l4*8];
    kfA[n][1] = *(const bf16x8*)&kb[(size_t)(n*16 + l15)*HDIM + 32 + l4*8];
  }

  auto body = [&](int kt, bf16x8 (&kfU)[4][2], bf16x8 (&kfP)[4][2], int ktp) {
    // ---- S^T = K Q (pure MFMA, prio 1): s[n][r] = S[key n*16+l4*4+r][q l15]
    f32x4 s[4] = {};
    __builtin_amdgcn_s_setprio(1);
    #pragma unroll
    for (int n = 0; n < 4; ++n) {
      s[n] = __builtin_amdgcn_mfma_f32_16x16x32_bf16(kfU[n][0], qf[0], s[n], 0, 0, 0);
      s[n] = __builtin_amdgcn_mfma_f32_16x16x32_bf16(kfU[n][1], qf[1], s[n], 0, 0, 0);
    }
    __builtin_amdgcn_s_setprio(0);
    // ---- issue V (current) + K (tile ktp) loads; hide under softmax ----
    bf16x8 vf[4][2];
    #pragma unroll
    for (int n = 0; n < 4; ++n) {
      vf[n][0] = *(const bf16x8*)&vb[(size_t)(n*16 + l15)*SEQ + kt + l4*8];
      vf[n][1] = *(const bf16x8*)&vb[(size_t)(n*16 + l15)*SEQ + kt + 32 + l4*8];
    }
    #pragma unroll
    for (int n = 0; n < 4; ++n) {
      kfP[n][0] = *(const bf16x8*)&kb[(size_t)(ktp + n*16 + l15)*HDIM + l4*8];
      kfP[n][1] = *(const bf16x8*)&kb[(size_t)(ktp + n*16 + l15)*HDIM + 32 + l4*8];
    }
    // ---- softmax: in-register trees + 2 shfl per reduction ----
    float c0 = fmaxf(fmaxf(s[0][0], s[0][1]), fmaxf(s[0][2], s[0][3]));
    float c1 = fmaxf(fmaxf(s[1][0], s[1][1]), fmaxf(s[1][2], s[1][3]));
    float c2 = fmaxf(fmaxf(s[2][0], s[2][1]), fmaxf(s[2][2], s[2][3]));
    float c3 = fmaxf(fmaxf(s[3][0], s[3][1]), fmaxf(s[3][2], s[3][3]));
    float smax = fmaxf(fmaxf(c0, c1), fmaxf(c2, c3));
    smax = fmaxf(smax, __shfl_xor(smax, 16));
    smax = fmaxf(smax, __shfl_xor(smax, 32));
    // T13 defer-max
    if (__any(smax > mrow + 8.f)) {
      float mn = fmaxf(mrow, smax);
      float alpha = __expf(mrow - mn);
      mrow = mn;
      lrow *= alpha;
      #pragma unroll
      for (int n = 0; n < 4; ++n)
        #pragma unroll
        for (int r = 0; r < 4; ++r)
          o[n][r] *= alpha;
    }
    #pragma unroll
    for (int n = 0; n < 4; ++n)
      #pragma unroll
      for (int r = 0; r < 4; ++r)
        s[n][r] = __expf(s[n][r] - mrow);
    float d0 = (s[0][0] + s[0][1]) + (s[0][2] + s[0][3]);
    float d1 = (s[1][0] + s[1][1]) + (s[1][2] + s[1][3]);
    float d2 = (s[2][0] + s[2][1]) + (s[2][2] + s[2][3]);
    float d3 = (s[3][0] + s[3][1]) + (s[3][2] + s[3][3]);
    float rsum = (d0 + d1) + (d2 + d3);
    rsum += __shfl_xor(rsum, 16);
    rsum += __shfl_xor(rsum, 32);
    lrow += rsum;
    // ---- P[q][key] -> LDS: 4x ds_write_b64 (keys l4*4+r consecutive) ----
    #pragma unroll
    for (int n = 0; n < 4; ++n) {
      unsigned int u0 = (unsigned int)f2bf(s[n][0]) | ((unsigned int)f2bf(s[n][1]) << 16);
      unsigned int u1 = (unsigned int)f2bf(s[n][2]) | ((unsigned int)f2bf(s[n][3]) << 16);
      uint2 uu = { u0, u1 };
      *(uint2*)&Pw[l15*72 + n*16 + l4*4] = uu;
    }
    // B-operand fragments: col=l15 <-> q, k=l4*8+j <-> key
    bf16x8 pa0 = *(const bf16x8*)&Pw[l15*72 + l4*8];
    bf16x8 pa1 = *(const bf16x8*)&Pw[l15*72 + 32 + l4*8];
    // ---- O^T += V^T P (pure MFMA, prio 1) ----
    __builtin_amdgcn_s_setprio(1);
    #pragma unroll
    for (int n = 0; n < 4; ++n) {
      o[n] = __builtin_amdgcn_mfma_f32_16x16x32_bf16(vf[n][0], pa0, o[n], 0, 0, 0);
      o[n] = __builtin_amdgcn_mfma_f32_16x16x32_bf16(vf[n][1], pa1, o[n], 0, 0, 0);
    }
    __builtin_amdgcn_s_setprio(0);
  };

  for (int kt = 0; kt < SEQ; kt += 128) {
    body(kt,      kfA, kfB, kt + 64);
    body(kt + 64, kfB, kfA, (kt + 128) & (SEQ - 1));  // last prefetch wraps (valid mem, unused)
  }

  // ---- epilogue: O/l -> ctx [B,S,D_MODEL] bf16, packed ushort4 stores ----
  const int b = bh >> 3, h = bh & 7;
  float inv = 1.0f / lrow;
  #pragma unroll
  for (int n = 0; n < 4; ++n) {
    ushort4 u = { f2bf(o[n][0]*inv), f2bf(o[n][1]*inv),
                  f2bf(o[n][2]*inv), f2bf(o[n][3]*inv) };
    *(ushort4*)&ctx[((size_t)(b*SEQ + q0 + l15))*D_MODEL + h*HDIM + n*16 + l4*4] = u;
  }
}

extern "C" void kernel_launch(void* const* d_in, const int* in_sizes, int n_in,
                              void* d_out, int out_size, void* d_ws, size_t ws_size,
                              hipStream_t stream) {
  const float* x  = (const float*)d_in[0];
  const float* Wq = (const float*)d_in[1];
  const float* bq = (const float*)d_in[2];
  const float* Wk = (const float*)d_in[3];
  const float* bk = (const float*)d_in[4];
  const float* Wv = (const float*)d_in[5];
  const float* bv = (const float*)d_in[6];
  const float* Wo = (const float*)d_in[7];
  const float* bo = (const float*)d_in[8];

  unsigned short* qw  = (unsigned short*)d_ws;                 // [B,H,S,Dh] bf16, 8 MB
  unsigned short* kw  = qw  + (size_t)MTOT*D_MODEL;            // [B,H,S,Dh] bf16, 8 MB
  unsigned short* vtw = kw  + (size_t)MTOT*D_MODEL;            // [B,H,Dh,S] bf16, 8 MB
  unsigned short* ctx = vtw + (size_t)MTOT*D_MODEL;            // [B,S,D]    bf16, 8 MB
  unsigned short* xb  = ctx + (size_t)MTOT*D_MODEL;            // [M,512]    bf16, 8 MB
  unsigned short* wqb = xb  + (size_t)MTOT*D_MODEL;            // 4x [512,512] bf16 contiguous
  unsigned short* wob = wqb + 3*(size_t)D_MODEL*D_MODEL;

  dim3 bb(256);
  cvt_k<<<2048, bb, 0, stream>>>(x, xb, MTOT*D_MODEL/4);
  cvt_w4<<<dim3(128, 4), bb, 0, stream>>>(Wq, Wk, Wv, Wo, wqb, D_MODEL*D_MODEL/4);

  gemm_qkv<<<dim3(MTOT/128, 12), bb, 0, stream>>>(xb, wqb, bq, bk, bv, qw, kw, vtw);
  attn_k<<<dim3(SEQ/64 * BATCH*NHEAD), bb, 0, stream>>>(qw, kw, vtw, ctx);
  gemm_out<<<dim3(MTOT/128, D_MODEL/128), bb, 0, stream>>>(ctx, wob, bo, (float*)d_out);
}

// Round 9
// 276.515 us; speedup vs baseline: 2.1473x; 2.1473x over previous
//
#include <hip/hip_runtime.h>
#include <hip/hip_bf16.h>

typedef __attribute__((ext_vector_type(8))) short bf16x8;
typedef __attribute__((ext_vector_type(4))) float f32x4;

#define D_MODEL 512
#define NHEAD 8
#define HDIM 64
#define SEQ 4096
#define BATCH 2
#define MTOT (BATCH*SEQ)   // 8192

__device__ __forceinline__ unsigned short f2bf(float f) {
  unsigned int u = __builtin_bit_cast(unsigned int, f);
  u += 0x7FFFu + ((u >> 16) & 1u);   // RNE
  return (unsigned short)(u >> 16);
}

// ---------------------------------------------------------------------------
// fp32 -> bf16 bulk convert (vectorized float4 -> ushort4)
// ---------------------------------------------------------------------------
__global__ __launch_bounds__(256)
void cvt_k(const float* __restrict__ src, unsigned short* __restrict__ dst, int n4) {
  int i = blockIdx.x * blockDim.x + threadIdx.x;
  int stride = gridDim.x * blockDim.x;
  for (; i < n4; i += stride) {
    float4 v = ((const float4*)src)[i];
    ushort4 u = { f2bf(v.x), f2bf(v.y), f2bf(v.z), f2bf(v.w) };
    ((ushort4*)dst)[i] = u;
  }
}

// 4 weight matrices in one launch: blockIdx.y picks the tensor.
__global__ __launch_bounds__(256)
void cvt_w4(const float* __restrict__ w0, const float* __restrict__ w1,
            const float* __restrict__ w2, const float* __restrict__ w3,
            unsigned short* __restrict__ dst, int n4each) {
  const float* srcs[4] = { w0, w1, w2, w3 };
  const float* src = srcs[blockIdx.y];
  unsigned short* d = dst + (size_t)blockIdx.y * n4each * 4;
  int i = blockIdx.x * blockDim.x + threadIdx.x;
  int stride = gridDim.x * blockDim.x;
  for (; i < n4each; i += stride) {
    float4 v = ((const float4*)src)[i];
    ushort4 u = { f2bf(v.x), f2bf(v.y), f2bf(v.z), f2bf(v.w) };
    ((ushort4*)(d))[i] = u;
  }
}

// ---------------------------------------------------------------------------
// Fused Q/K/V projection GEMM. Grid (MTOT/128, 12): blockIdx.y>>2 selects
// {Q,K,V}; (blockIdx.y&3)*128 is the 128-wide N-tile within that projection.
// W4 = [Wq;Wk;Wv] contiguous bf16 [3*512,512]. m97 staging structure.
// Q scaled by 1/8 (folds 1/sqrt(Dh)); Q,K written [B,H,S,Dh]; V written
// [B,H,Dh,S] (transposed for PV fragment loads).
// ---------------------------------------------------------------------------
__global__ __launch_bounds__(256)
void gemm_qkv(const unsigned short* __restrict__ A,
              const unsigned short* __restrict__ W4,
              const float* __restrict__ bq, const float* __restrict__ bk,
              const float* __restrict__ bv,
              unsigned short* __restrict__ qw, unsigned short* __restrict__ kw,
              unsigned short* __restrict__ vtw) {
  __shared__ unsigned short Als[128*64];
  __shared__ unsigned short Bls[128*64];
  const int tid = threadIdx.x;
  const int lane = tid & 63, wid = tid >> 6;
  const int wr = wid >> 1, wc = wid & 1;
  const int l15 = lane & 15, l4 = lane >> 4;
  const int m0 = blockIdx.x * 128;
  const int which = blockIdx.y >> 2;            // 0=Q 1=K 2=V
  const int n0 = (blockIdx.y & 3) * 128;
  const unsigned short* Bw = W4 + (size_t)which * D_MODEL * D_MODEL;
  const float* bias = which == 0 ? bq : (which == 1 ? bk : bv);
  unsigned short* outp = which == 0 ? qw : (which == 1 ? kw : vtw);
  const float scale = which == 0 ? 0.125f : 1.0f;
  const int srow = lane >> 3;
  const int scol = (lane & 7) * 8;
  f32x4 acc[4][4] = {};

  for (int kt = 0; kt < D_MODEL; kt += 64) {
    #pragma unroll
    for (int j = 0; j < 4; ++j) {
      int r = wid*32 + j*8 + srow;
      __builtin_amdgcn_global_load_lds(
        (const __attribute__((address_space(1))) unsigned int*)(A + (size_t)(m0 + r)*D_MODEL + kt + scol),
        (__attribute__((address_space(3))) unsigned int*)(&Als[r*64 + scol]), 16, 0, 0);
      __builtin_amdgcn_global_load_lds(
        (const __attribute__((address_space(1))) unsigned int*)(Bw + (size_t)(n0 + r)*D_MODEL + kt + scol),
        (__attribute__((address_space(3))) unsigned int*)(&Bls[r*64 + scol]), 16, 0, 0);
    }
    __syncthreads();
    #pragma unroll
    for (int ks = 0; ks < 2; ++ks) {
      bf16x8 a[4], b[4];
      #pragma unroll
      for (int m = 0; m < 4; ++m)
        a[m] = *(const bf16x8*)&Als[(wr*64 + m*16 + l15)*64 + ks*32 + l4*8];
      #pragma unroll
      for (int n = 0; n < 4; ++n)
        b[n] = *(const bf16x8*)&Bls[(wc*64 + n*16 + l15)*64 + ks*32 + l4*8];
      #pragma unroll
      for (int m = 0; m < 4; ++m)
        #pragma unroll
        for (int n = 0; n < 4; ++n)
          acc[m][n] = __builtin_amdgcn_mfma_f32_16x16x32_bf16(a[m], b[n], acc[m][n], 0, 0, 0);
    }
    __syncthreads();
  }

  #pragma unroll
  for (int n = 0; n < 4; ++n) {
    int gn = n0 + wc*64 + n*16 + l15;
    float bvv = bias[gn];
    int h = gn >> 6, d = gn & 63;
    #pragma unroll
    for (int m = 0; m < 4; ++m) {
      int gmb = m0 + wr*64 + m*16 + l4*4;
      #pragma unroll
      for (int r = 0; r < 4; ++r) {
        int gm = gmb + r;
        int b = gm >> 12, s = gm & 4095;
        float val = (acc[m][n][r] + bvv) * scale;
        if (which != 2)
          outp[((size_t)((b*NHEAD + h)*SEQ + s))*HDIM + d] = f2bf(val);
        else
          outp[((size_t)((b*NHEAD + h)*HDIM + d))*SEQ + s] = f2bf(val);
      }
    }
  }
}

// ---------------------------------------------------------------------------
// Output-projection GEMM (A bf16 ctx, W bf16, fp32 out [M,N]). m97 structure.
// ---------------------------------------------------------------------------
__global__ __launch_bounds__(256)
void gemm_out(const unsigned short* __restrict__ A,
              const unsigned short* __restrict__ Bw,
              const float* __restrict__ bias, float* __restrict__ out) {
  __shared__ unsigned short Als[128*64];
  __shared__ unsigned short Bls[128*64];
  const int tid = threadIdx.x;
  const int lane = tid & 63, wid = tid >> 6;
  const int wr = wid >> 1, wc = wid & 1;
  const int l15 = lane & 15, l4 = lane >> 4;
  const int m0 = blockIdx.x * 128;
  const int n0 = blockIdx.y * 128;
  const int srow = lane >> 3;
  const int scol = (lane & 7) * 8;
  f32x4 acc[4][4] = {};

  for (int kt = 0; kt < D_MODEL; kt += 64) {
    #pragma unroll
    for (int j = 0; j < 4; ++j) {
      int r = wid*32 + j*8 + srow;
      __builtin_amdgcn_global_load_lds(
        (const __attribute__((address_space(1))) unsigned int*)(A + (size_t)(m0 + r)*D_MODEL + kt + scol),
        (__attribute__((address_space(3))) unsigned int*)(&Als[r*64 + scol]), 16, 0, 0);
      __builtin_amdgcn_global_load_lds(
        (const __attribute__((address_space(1))) unsigned int*)(Bw + (size_t)(n0 + r)*D_MODEL + kt + scol),
        (__attribute__((address_space(3))) unsigned int*)(&Bls[r*64 + scol]), 16, 0, 0);
    }
    __syncthreads();
    #pragma unroll
    for (int ks = 0; ks < 2; ++ks) {
      bf16x8 a[4], b[4];
      #pragma unroll
      for (int m = 0; m < 4; ++m)
        a[m] = *(const bf16x8*)&Als[(wr*64 + m*16 + l15)*64 + ks*32 + l4*8];
      #pragma unroll
      for (int n = 0; n < 4; ++n)
        b[n] = *(const bf16x8*)&Bls[(wc*64 + n*16 + l15)*64 + ks*32 + l4*8];
      #pragma unroll
      for (int m = 0; m < 4; ++m)
        #pragma unroll
        for (int n = 0; n < 4; ++n)
          acc[m][n] = __builtin_amdgcn_mfma_f32_16x16x32_bf16(a[m], b[n], acc[m][n], 0, 0, 0);
    }
    __syncthreads();
  }

  #pragma unroll
  for (int n = 0; n < 4; ++n) {
    int gn = n0 + wc*64 + n*16 + l15;
    float bv = bias[gn];
    #pragma unroll
    for (int m = 0; m < 4; ++m) {
      int gmb = m0 + wr*64 + m*16 + l4*4;
      #pragma unroll
      for (int r = 0; r < 4; ++r)
        out[(size_t)(gmb + r)*D_MODEL + gn] = acc[m][n][r] + bv;
    }
  }
}

// ---------------------------------------------------------------------------
// Flash attention v4: BLOCK-SHARED LDS K/V STAGING.
// Round-7 post-mortem: per-wave K/V streaming from L2 (16KB/wave/tile, zero
// block sharing + unpipelined load latency) explains the 18k cyc/tile wall
// with MfmaUtil/VALUBusy both idle; spill-to-scratch theory refuted by absent
// scratch traffic (FETCH 12MB). Fix = §5 staging idiom (validated on this HW
// by the GEMMs): K,V tiles staged per BLOCK via global_load_lds (4x less L2
// traffic, LDS-latency reads), single-buffered, 2 barriers/tile.
// Source-side XOR swizzle (m173/m201, rule #21: dest stays linear):
//   LDS slot (row, col16) holds global chunk col16 ^ (row&7)  [16B units]
//   read col16 = (ks*4+l4) ^ (l15&7)  -> ~4-way conflict (1.58x), not 32-way.
// Swapped-operand math unchanged (HW-validated r4/r7, absmax 4.9e-4):
//   s[n][r]=S[key][q=l15]; P via 4x ds_write_b64 + 2x ds_read_b128;
//   o[n][r]=O[d][q=l15]. V frags read JIT from LDS at PV (no vf buffer ->
//   ~70-reg live set). T1 XCD swizzle; T5 setprio; T13 defer-max.
// LDS: K 8KB + V 8KB + P 9KB = 25.6KB -> 4 blocks/CU (grid-limited).
// ---------------------------------------------------------------------------
__global__ __launch_bounds__(256)
void attn_k(const unsigned short* __restrict__ qw,
            const unsigned short* __restrict__ kw,
            const unsigned short* __restrict__ vtw,
            unsigned short* __restrict__ ctx) {
  __shared__ unsigned short Kls[64*64];     // [key][d], 16B chunks XOR-swizzled
  __shared__ unsigned short Vls[64*64];     // [d][key], 16B chunks XOR-swizzled
  __shared__ unsigned short Pls[4][16*72];
  const int tid = threadIdx.x;
  const int lane = tid & 63, wid = tid >> 6;
  const int l15 = lane & 15, l4 = lane >> 4;
  const int bid = blockIdx.x;
  const int swz = (bid & 7) * 128 + (bid >> 3);   // bijective: 1024 = 8*128
  const int bh = swz >> 6;                        // b*8 + h, 0..15
  const int q0 = (swz & 63) * 64 + wid * 16;      // this wave's first q row
  const unsigned short* qb = qw + (size_t)bh * SEQ * HDIM;
  const unsigned short* kb = kw + (size_t)bh * SEQ * HDIM;
  const unsigned short* vb = vtw + (size_t)bh * HDIM * SEQ;
  unsigned short* Pw = &Pls[wid][0];

  // staging coords: slot = i*256 + tid; 8 chunks (16B) per 64-elem row
  const int srow0 = tid >> 3;          // slot row for i=0 (0..31)
  const int scol0 = tid & 7;           // chunk col 0..7

  // Q fragments (B-operand): col=l15 <-> q, k=l4*8+j <-> d.
  bf16x8 qf0 = *(const bf16x8*)&qb[(size_t)(q0 + l15)*HDIM + l4*8];
  bf16x8 qf1 = *(const bf16x8*)&qb[(size_t)(q0 + l15)*HDIM + 32 + l4*8];

  f32x4 o[4] = {};                 // o[n][r] = O[d=n*16+l4*4+r][q=l15]
  float mrow = -1e30f, lrow = 0.f; // scalar per lane (one q per lane)

  for (int kt = 0; kt < SEQ; kt += 64) {
    __syncthreads();   // all waves done reading previous tile's K/V
    // ---- stage K,V tile kt: linear LDS dest, XOR-swizzled global source ----
    #pragma unroll
    for (int i = 0; i < 2; ++i) {
      int row = i*32 + srow0;
      int cg = scol0 ^ (row & 7);
      __builtin_amdgcn_global_load_lds(
        (const __attribute__((address_space(1))) unsigned int*)(kb + (size_t)(kt + row)*HDIM + cg*8),
        (__attribute__((address_space(3))) unsigned int*)(&Kls[(i*256 + tid)*8]), 16, 0, 0);
      __builtin_amdgcn_global_load_lds(
        (const __attribute__((address_space(1))) unsigned int*)(vb + (size_t)row*SEQ + kt + cg*8),
        (__attribute__((address_space(3))) unsigned int*)(&Vls[(i*256 + tid)*8]), 16, 0, 0);
    }
    __syncthreads();   // staged data visible (vmcnt drained before barrier)

    // ---- S^T = K Q from LDS (A-frag: row=key=n*16+l15, k=d) ----
    f32x4 s[4] = {};
    __builtin_amdgcn_s_setprio(1);
    #pragma unroll
    for (int n = 0; n < 4; ++n) {
      const int krow = n*16 + l15;
      bf16x8 k0 = *(const bf16x8*)&Kls[krow*64 + ((l4     ^ (l15 & 7))*8)];
      bf16x8 k1 = *(const bf16x8*)&Kls[krow*64 + (((4+l4) ^ (l15 & 7))*8)];
      s[n] = __builtin_amdgcn_mfma_f32_16x16x32_bf16(k0, qf0, s[n], 0, 0, 0);
      s[n] = __builtin_amdgcn_mfma_f32_16x16x32_bf16(k1, qf1, s[n], 0, 0, 0);
    }
    __builtin_amdgcn_s_setprio(0);

    // ---- softmax: in-register trees + 2 shfl per reduction ----
    float c0 = fmaxf(fmaxf(s[0][0], s[0][1]), fmaxf(s[0][2], s[0][3]));
    float c1 = fmaxf(fmaxf(s[1][0], s[1][1]), fmaxf(s[1][2], s[1][3]));
    float c2 = fmaxf(fmaxf(s[2][0], s[2][1]), fmaxf(s[2][2], s[2][3]));
    float c3 = fmaxf(fmaxf(s[3][0], s[3][1]), fmaxf(s[3][2], s[3][3]));
    float smax = fmaxf(fmaxf(c0, c1), fmaxf(c2, c3));
    smax = fmaxf(smax, __shfl_xor(smax, 16));
    smax = fmaxf(smax, __shfl_xor(smax, 32));
    // T13 defer-max (THR=8)
    if (__any(smax > mrow + 8.f)) {
      float mn = fmaxf(mrow, smax);
      float alpha = __expf(mrow - mn);
      mrow = mn;
      lrow *= alpha;
      #pragma unroll
      for (int n = 0; n < 4; ++n)
        #pragma unroll
        for (int r = 0; r < 4; ++r)
          o[n][r] *= alpha;
    }
    #pragma unroll
    for (int n = 0; n < 4; ++n)
      #pragma unroll
      for (int r = 0; r < 4; ++r)
        s[n][r] = __expf(s[n][r] - mrow);
    float d0 = (s[0][0] + s[0][1]) + (s[0][2] + s[0][3]);
    float d1 = (s[1][0] + s[1][1]) + (s[1][2] + s[1][3]);
    float d2 = (s[2][0] + s[2][1]) + (s[2][2] + s[2][3]);
    float d3 = (s[3][0] + s[3][1]) + (s[3][2] + s[3][3]);
    float rsum = (d0 + d1) + (d2 + d3);
    rsum += __shfl_xor(rsum, 16);
    rsum += __shfl_xor(rsum, 32);
    lrow += rsum;

    // ---- P[q][key] -> LDS: 4x ds_write_b64 (keys l4*4+r consecutive) ----
    #pragma unroll
    for (int n = 0; n < 4; ++n) {
      unsigned int u0 = (unsigned int)f2bf(s[n][0]) | ((unsigned int)f2bf(s[n][1]) << 16);
      unsigned int u1 = (unsigned int)f2bf(s[n][2]) | ((unsigned int)f2bf(s[n][3]) << 16);
      uint2 uu = { u0, u1 };
      *(uint2*)&Pw[l15*72 + n*16 + l4*4] = uu;
    }
    // B-operand fragments: col=l15 <-> q, k=l4*8+j <-> key
    bf16x8 pa0 = *(const bf16x8*)&Pw[l15*72 + l4*8];
    bf16x8 pa1 = *(const bf16x8*)&Pw[l15*72 + 32 + l4*8];

    // ---- O^T += V^T P: V frags JIT from LDS (A-frag: row=d=n*16+l15, k=key)
    __builtin_amdgcn_s_setprio(1);
    #pragma unroll
    for (int n = 0; n < 4; ++n) {
      const int vrow = n*16 + l15;
      bf16x8 v0 = *(const bf16x8*)&Vls[vrow*64 + ((l4     ^ (l15 & 7))*8)];
      bf16x8 v1 = *(const bf16x8*)&Vls[vrow*64 + (((4+l4) ^ (l15 & 7))*8)];
      o[n] = __builtin_amdgcn_mfma_f32_16x16x32_bf16(v0, pa0, o[n], 0, 0, 0);
      o[n] = __builtin_amdgcn_mfma_f32_16x16x32_bf16(v1, pa1, o[n], 0, 0, 0);
    }
    __builtin_amdgcn_s_setprio(0);
  }

  // ---- epilogue: O/l -> ctx [B,S,D_MODEL] bf16, packed ushort4 stores ----
  const int b = bh >> 3, h = bh & 7;
  float inv = 1.0f / lrow;
  #pragma unroll
  for (int n = 0; n < 4; ++n) {
    ushort4 u = { f2bf(o[n][0]*inv), f2bf(o[n][1]*inv),
                  f2bf(o[n][2]*inv), f2bf(o[n][3]*inv) };
    *(ushort4*)&ctx[((size_t)(b*SEQ + q0 + l15))*D_MODEL + h*HDIM + n*16 + l4*4] = u;
  }
}

extern "C" void kernel_launch(void* const* d_in, const int* in_sizes, int n_in,
                              void* d_out, int out_size, void* d_ws, size_t ws_size,
                              hipStream_t stream) {
  const float* x  = (const float*)d_in[0];
  const float* Wq = (const float*)d_in[1];
  const float* bq = (const float*)d_in[2];
  const float* Wk = (const float*)d_in[3];
  const float* bk = (const float*)d_in[4];
  const float* Wv = (const float*)d_in[5];
  const float* bv = (const float*)d_in[6];
  const float* Wo = (const float*)d_in[7];
  const float* bo = (const float*)d_in[8];

  unsigned short* qw  = (unsigned short*)d_ws;                 // [B,H,S,Dh] bf16, 8 MB
  unsigned short* kw  = qw  + (size_t)MTOT*D_MODEL;            // [B,H,S,Dh] bf16, 8 MB
  unsigned short* vtw = kw  + (size_t)MTOT*D_MODEL;            // [B,H,Dh,S] bf16, 8 MB
  unsigned short* ctx = vtw + (size_t)MTOT*D_MODEL;            // [B,S,D]    bf16, 8 MB
  unsigned short* xb  = ctx + (size_t)MTOT*D_MODEL;            // [M,512]    bf16, 8 MB
  unsigned short* wqb = xb  + (size_t)MTOT*D_MODEL;            // 4x [512,512] bf16 contiguous
  unsigned short* wob = wqb + 3*(size_t)D_MODEL*D_MODEL;

  dim3 bb(256);
  cvt_k<<<2048, bb, 0, stream>>>(x, xb, MTOT*D_MODEL/4);
  cvt_w4<<<dim3(128, 4), bb, 0, stream>>>(Wq, Wk, Wv, Wo, wqb, D_MODEL*D_MODEL/4);

  gemm_qkv<<<dim3(MTOT/128, 12), bb, 0, stream>>>(xb, wqb, bq, bk, bv, qw, kw, vtw);
  attn_k<<<dim3(SEQ/64 * BATCH*NHEAD), bb, 0, stream>>>(qw, kw, vtw, ctx);
  gemm_out<<<dim3(MTOT/128, D_MODEL/128), bb, 0, stream>>>(ctx, wob, bo, (float*)d_out);
}